// Round 1
// baseline (296.745 us; speedup 1.0000x reference)
//
#include <hip/hip_runtime.h>

#define Hd   128
#define Wd   128
#define CIN  64
#define COUT 64
#define Bn   8
#define KK   9
#define OCF  18   // offset channels = 2*K*K

// ---- repack weights for scalar-friendly access ----
// w_off: [18][64][3][3] -> w_off_t: [ci][kk][oc]  (oc contiguous, 18)
// w    : [64][64][3][3] -> w_t    : [kk][ci][co]  (co contiguous, 64)
__global__ __launch_bounds__(256) void repack_kernel(
    const float* __restrict__ w_off, const float* __restrict__ w,
    float* __restrict__ w_off_t, float* __restrict__ w_t) {
  int i = blockIdx.x * 256 + threadIdx.x;
  if (i < OCF * CIN * KK) {
    int oc = i / (CIN * KK);
    int r  = i - oc * (CIN * KK);
    int ci = r / KK;
    int kk = r - ci * KK;
    w_off_t[(ci * KK + kk) * OCF + oc] = w_off[i];
  }
  if (i < COUT * CIN * KK) {
    int co = i / (CIN * KK);
    int r  = i - co * (CIN * KK);
    int ci = r / KK;
    int kk = r - ci * KK;
    w_t[(kk * CIN + ci) * COUT + co] = w[i];
  }
}

__global__ __launch_bounds__(256, 2) void deform_conv_kernel(
    const float* __restrict__ x, const float* __restrict__ b_off,
    const float* __restrict__ w_off_t, const float* __restrict__ w_t,
    float* __restrict__ out) {
  int t  = blockIdx.x * 256 + threadIdx.x;
  int wo = t & (Wd - 1);
  int ho = (t >> 7) & (Hd - 1);
  int b  = t >> 14;
  const float* xb = x + (size_t)b * CIN * Hd * Wd;

  // ---------------- stage 1: 3x3 offset conv (18 channels) ----------------
  float accoff[OCF];
#pragma unroll
  for (int i = 0; i < OCF; ++i) accoff[i] = 0.f;

  int  offs[9];
  bool val[9];
#pragma unroll
  for (int kk = 0; kk < 9; ++kk) {
    int yy = ho - 1 + kk / 3;
    int xx = wo - 1 + kk % 3;
    val[kk]  = (yy >= 0) && (yy < Hd) && (xx >= 0) && (xx < Wd);
    offs[kk] = yy * Wd + xx;
  }

  for (int ci = 0; ci < CIN; ++ci) {
    const float* xp = xb + ci * (Hd * Wd);
    const float* wp = w_off_t + ci * (KK * OCF);
    float xv[9];
#pragma unroll
    for (int kk = 0; kk < 9; ++kk) xv[kk] = val[kk] ? xp[offs[kk]] : 0.f;
#pragma unroll
    for (int kk = 0; kk < 9; ++kk) {
#pragma unroll
      for (int oc = 0; oc < OCF; ++oc)
        accoff[oc] = fmaf(wp[kk * OCF + oc], xv[kk], accoff[oc]);
    }
  }

  float dyv[9], dxv[9];
#pragma unroll
  for (int kk = 0; kk < 9; ++kk) {
    dyv[kk] = accoff[2 * kk]     + b_off[2 * kk];
    dxv[kk] = accoff[2 * kk + 1] + b_off[2 * kk + 1];
  }

  // ---------------- stage 2: bilinear sample + contraction ----------------
  float acc[COUT];
#pragma unroll
  for (int i = 0; i < COUT; ++i) acc[i] = 0.f;

#pragma unroll
  for (int kk = 0; kk < 9; ++kk) {
    float py = (float)(ho - 1 + kk / 3) + dyv[kk];
    float px = (float)(wo - 1 + kk % 3) + dxv[kk];
    float y0f = floorf(py), x0f = floorf(px);
    float wy1 = py - y0f, wy0 = 1.f - wy1;
    float wx1 = px - x0f, wx0 = 1.f - wx1;
    float y1f = y0f + 1.f, x1f = x0f + 1.f;
    bool vy0 = (y0f >= 0.f) && (y0f < (float)Hd);
    bool vy1 = (y1f >= 0.f) && (y1f < (float)Hd);
    bool vx0 = (x0f >= 0.f) && (x0f < (float)Wd);
    bool vx1 = (x1f >= 0.f) && (x1f < (float)Wd);
    float w00 = wy0 * wx0 * ((vy0 && vx0) ? 1.f : 0.f);
    float w01 = wy0 * wx1 * ((vy0 && vx1) ? 1.f : 0.f);
    float w10 = wy1 * wx0 * ((vy1 && vx0) ? 1.f : 0.f);
    float w11 = wy1 * wx1 * ((vy1 && vx1) ? 1.f : 0.f);
    int y0 = (int)fminf(fmaxf(y0f, 0.f), (float)(Hd - 1));
    int y1 = (int)fminf(fmaxf(y1f, 0.f), (float)(Hd - 1));
    int x0 = (int)fminf(fmaxf(x0f, 0.f), (float)(Wd - 1));
    int x1 = (int)fminf(fmaxf(x1f, 0.f), (float)(Wd - 1));
    int o00 = y0 * Wd + x0, o01 = y0 * Wd + x1;
    int o10 = y1 * Wd + x0, o11 = y1 * Wd + x1;

    const float* wpk = w_t + kk * CIN * COUT;
    for (int ci = 0; ci < CIN; ++ci) {
      const float* xp = xb + ci * (Hd * Wd);
      float v = w00 * xp[o00] + w01 * xp[o01] + w10 * xp[o10] + w11 * xp[o11];
      const float* wp = wpk + ci * COUT;
#pragma unroll
      for (int co = 0; co < COUT; ++co)
        acc[co] = fmaf(wp[co], v, acc[co]);
    }
  }

  float* op = out + (size_t)b * COUT * Hd * Wd + ho * Wd + wo;
#pragma unroll
  for (int co = 0; co < COUT; ++co)
    op[co * (Hd * Wd)] = acc[co];
}

extern "C" void kernel_launch(void* const* d_in, const int* in_sizes, int n_in,
                              void* d_out, int out_size, void* d_ws, size_t ws_size,
                              hipStream_t stream) {
  const float* x     = (const float*)d_in[0];
  const float* w_off = (const float*)d_in[1];
  const float* b_off = (const float*)d_in[2];
  const float* w     = (const float*)d_in[3];
  float* out = (float*)d_out;

  float* w_off_t = (float*)d_ws;            // 10368 floats (pad to 16384)
  float* w_t     = w_off_t + 16384;         // 36864 floats

  repack_kernel<<<(COUT * CIN * KK + 255) / 256, 256, 0, stream>>>(
      w_off, w, w_off_t, w_t);

  int total = Bn * Hd * Wd;                 // 131072 threads
  deform_conv_kernel<<<total / 256, 256, 0, stream>>>(
      x, b_off, w_off_t, w_t, out);
}